// Round 12
// baseline (359.081 us; speedup 1.0000x reference)
//
#include <hip/hip_runtime.h>
#include <hip/hip_bf16.h>
#include <stdint.h>

#define NIMG 96
#define N 512
#define IMG (N*N)
#define OUT_PLANE ((long long)NIMG * IMG)

typedef __attribute__((ext_vector_type(8))) _Float16 f16x8;
typedef __attribute__((ext_vector_type(4))) float f32x4;
typedef unsigned short u16;

__device__ __forceinline__ u16 f2h(float v) {
    _Float16 h = (_Float16)v;
    return __builtin_bit_cast(u16, h);
}

__device__ __forceinline__ void gload16(const void* g, void* l) {
    __builtin_amdgcn_global_load_lds(
        (const __attribute__((address_space(1))) void*)g,
        (__attribute__((address_space(3))) void*)l, 16, 0, 0);
}

// ===========================================================================
// Parity fold: D[k][511-m] = (-1)^k D[k][m]  (exact).
// Every K=512 GEMM vs D splits into two K=256 GEMMs vs 256x256 half-matrices
//   De[k'][m] = D[2k'][m],  Do[k'][m] = D[2k'+1][m]   (m < 256).
// Forward: T1[2k'] = De @ (x + x_mirror), T1[2k'+1] = Do @ (x - x_mirror).
// Inverse: U[n] = Ue[n]+Uo[n], U[511-n] = Ue[n]-Uo[n]  (n<256),
//   Ue = (DeT) @ Y_even_rows, Uo = (DoT) @ Y_odd_rows.
// Second inverse stages (HH/HL/LH = U* @ D) stay unfolded on the proven
// R11 invC engine.
// ===========================================================================

// ---------------------------------------------------------------------------
// convF: x -> Xp_cm/Xm_cm (f16 col-major folded halves), outLL = x.
// Blocks with flat id < 1024 also build Dcm (512x512) and De/Do/DeT/DoT
// (256x256 each); D is only read by later dispatches.
// ---------------------------------------------------------------------------
__global__ __launch_bounds__(256) void convF(const float* __restrict__ x,
                                             u16* __restrict__ Xp,
                                             u16* __restrict__ Xm,
                                             float* __restrict__ outLL,
                                             u16* __restrict__ Dcm,
                                             u16* __restrict__ De,
                                             u16* __restrict__ Do_,
                                             u16* __restrict__ DeT,
                                             u16* __restrict__ DoT) {
    const int bid = blockIdx.x + (blockIdx.y << 4) + (blockIdx.z << 7);
    if (bid < 1024) {
        int idx = (bid << 8) + threadIdx.x;
        int k = idx >> 9, m = idx & 511;
        int r = ((2 * m + 1) * k) & 2047;          // exact angle reduction mod 4N
        float c = cospif((float)r * (1.0f / 1024.0f));
        float s = (k == 0) ? 0.04419417382415922f : 0.0625f;
        u16 h = f2h(c * s);
        Dcm[(m << 9) + k] = h;
        if (m < 256) {
            int kh = k >> 1;
            if ((k & 1) == 0) { De[(kh << 8) + m] = h;  DeT[(m << 8) + kh] = h; }
            else              { Do_[(kh << 8) + m] = h; DoT[(m << 8) + kh] = h; }
        }
    }

    __shared__ float sP[32][33], sM[32][33];
    const long long base = (long long)blockIdx.z * IMG;
    const int r0 = blockIdx.y * 32, c0 = blockIdx.x * 32;   // r0 < 256
    const int tr = threadIdx.x >> 3;
    const int tc = (threadIdx.x & 7) * 4;
    float4 a = *(const float4*)&x[base + (long long)(r0 + tr) * N + c0 + tc];
    float4 b = *(const float4*)&x[base + (long long)(511 - r0 - tr) * N + c0 + tc];
    *(float4*)&outLL[base + (long long)(r0 + tr) * N + c0 + tc] = a;
    *(float4*)&outLL[base + (long long)(511 - r0 - tr) * N + c0 + tc] = b;
    sP[tr][tc + 0] = a.x + b.x; sP[tr][tc + 1] = a.y + b.y;
    sP[tr][tc + 2] = a.z + b.z; sP[tr][tc + 3] = a.w + b.w;
    sM[tr][tc + 0] = a.x - b.x; sM[tr][tc + 1] = a.y - b.y;
    sM[tr][tc + 2] = a.z - b.z; sM[tr][tc + 3] = a.w - b.w;
    __syncthreads();
    ushort4 hp, hm;
    hp.x = f2h(sP[tc + 0][tr]); hp.y = f2h(sP[tc + 1][tr]);
    hp.z = f2h(sP[tc + 2][tr]); hp.w = f2h(sP[tc + 3][tr]);
    hm.x = f2h(sM[tc + 0][tr]); hm.y = f2h(sM[tc + 1][tr]);
    hm.z = f2h(sM[tc + 2][tr]); hm.w = f2h(sM[tc + 3][tr]);
    const long long pb = (long long)blockIdx.z * 131072;
    *(ushort4*)&Xp[pb + (long long)(c0 + tr) * 256 + r0 + tc] = hp;
    *(ushort4*)&Xm[pb + (long long)(c0 + tr) * 256 + r0 + tc] = hm;
}

// ===========================================================================
// Proven GEMM engine (R6/R11): 128x128 tile, BK=32, 4 waves, dbuf LDS,
// global_load_lds width-16 staging, mfma_f32_16x16x32_f16.
// C = A(row-major) * B(col-major storage: stored[n][k] = op(B)[k][n]).
// ===========================================================================
#define GEMM_DECLS                                                         \
    const int tid = threadIdx.x;                                           \
    const int wave = tid >> 6;                                             \
    const int lane = tid & 63;                                             \
    const int srow = lane >> 2;                                            \
    const int sc8  = (lane & 3) * 8;                                       \
    const int war  = wave * 32;                                            \
    const int fr   = lane & 15;                                            \
    const int kg8  = (lane >> 4) * 8;                                      \
    const int wr   = (wave >> 1) * 64;                                     \
    const int wc   = (wave & 1) * 64;                                      \
    const int rb   = (lane >> 4) * 4;                                      \
    int aoff[4], boff[4];                                                  \
    _Pragma("unroll")                                                      \
    for (int i = 0; i < 4; ++i) {                                          \
        aoff[i] = (wr + i * 16 + fr) * 32 + kg8;                           \
        boff[i] = (wc + i * 16 + fr) * 32 + kg8;                           \
    }                                                                      \
    f32x4 acc[4][4];                                                       \
    _Pragma("unroll")                                                      \
    for (int i = 0; i < 4; ++i)                                            \
        _Pragma("unroll")                                                  \
        for (int j = 0; j < 4; ++j)                                        \
            acc[i][j] = (f32x4){0.0f, 0.0f, 0.0f, 0.0f};

#define GEMM_LOOP(Ab, lda, Bb, ldb, Keff)                                  \
    {                                                                      \
        auto stage = [&](int buf, int k0) {                                \
            _Pragma("unroll")                                              \
            for (int i = 0; i < 2; ++i) {                                  \
                int r = war + i * 16;                                      \
                gload16((Ab) + (long long)(m0 + r + srow) * (lda) + k0 + sc8, &As[buf][r * 32]); \
                gload16((Bb) + (long long)(n0 + r + srow) * (ldb) + k0 + sc8, &Bs[buf][r * 32]); \
            }                                                              \
        };                                                                 \
        auto compute = [&](int buf) {                                      \
            f16x8 af[4], bf[4];                                            \
            _Pragma("unroll")                                              \
            for (int i = 0; i < 4; ++i) af[i] = *(const f16x8*)&As[buf][aoff[i]]; \
            _Pragma("unroll")                                              \
            for (int j = 0; j < 4; ++j) bf[j] = *(const f16x8*)&Bs[buf][boff[j]]; \
            _Pragma("unroll")                                              \
            for (int i = 0; i < 4; ++i)                                    \
                _Pragma("unroll")                                          \
                for (int j = 0; j < 4; ++j)                                \
                    acc[i][j] = __builtin_amdgcn_mfma_f32_16x16x32_f16(af[i], bf[j], acc[i][j], 0, 0, 0); \
        };                                                                 \
        const int nb = (Keff) >> 5;                                        \
        stage(0, 0);                                                       \
        __syncthreads();                                                   \
        int cur = 0;                                                       \
        for (int t = 0; t < nb - 1; ++t) {                                 \
            stage(cur ^ 1, (t + 1) * 32);                                  \
            compute(cur);                                                  \
            __syncthreads();                                               \
            cur ^= 1;                                                      \
        }                                                                  \
        compute(cur);                                                      \
    }

#define EPI_F16_RM(Cb, ldc)                                                \
    _Pragma("unroll")                                                      \
    for (int i = 0; i < 4; ++i)                                            \
        _Pragma("unroll")                                                  \
        for (int j = 0; j < 4; ++j) {                                      \
            int r = m0 + wr + i * 16 + rb;                                 \
            int c = n0 + wc + j * 16 + fr;                                 \
            _Pragma("unroll")                                              \
            for (int g = 0; g < 4; ++g)                                    \
                (Cb)[(long long)(r + g) * (ldc) + c] = f2h(acc[i][j][g]);  \
        }

// ---------------------------------------------------------------------------
// gemmF1: T1e = De @ Xp, T1o = Do @ Xm.  id in [0,16): [0,8)=e, [8,16)=o;
// within: m0 = ((sub>>2)&1)*128 (M=256), n0 = (sub&3)*128 (N=512). K=256.
// Output row-major f16 256x512 (pitch 512).
// ---------------------------------------------------------------------------
__global__ __launch_bounds__(256) void gemmF1(
    const u16* __restrict__ De, const u16* __restrict__ Do_,
    const u16* __restrict__ Xp, const u16* __restrict__ Xm,
    u16* __restrict__ T1e, u16* __restrict__ T1o)
{
    __shared__ u16 As[2][128 * 32];
    __shared__ u16 Bs[2][128 * 32];
    const int bz = blockIdx.z;
    const int id = blockIdx.x;
    const int p = id >> 3, sub = id & 7;
    const int m0 = ((sub >> 2) & 1) * 128;
    const int n0 = (sub & 3) * 128;
    const u16* __restrict__ Ab = p ? Do_ : De;                           // lda 256
    const u16* __restrict__ Bb = (p ? Xm : Xp) + (long long)bz * 131072; // ldb 256
    u16* __restrict__ Cb = (p ? T1o : T1e) + (long long)bz * 131072;     // ldc 512

    GEMM_DECLS
    GEMM_LOOP(Ab, 256, Bb, 256, 256)
    EPI_F16_RM(Cb, 512)
}

// ---------------------------------------------------------------------------
// foldT1: T1p[2k'+p][j] = T1{p}[k'][j] + T1{p}[k'][511-j],  T1m with minus.
// T1p/T1m: 512x256 row-major f16.
// ---------------------------------------------------------------------------
__global__ __launch_bounds__(256) void foldT1(
    const u16* __restrict__ T1e, const u16* __restrict__ T1o,
    u16* __restrict__ T1p, u16* __restrict__ T1m)
{
    int t = blockIdx.x * 256 + threadIdx.x;          // 96*16384 total
    int img = t >> 14;
    int rem = t & 16383;
    int p = rem >> 13;
    int k = (rem >> 5) & 255;
    int j0 = (rem & 31) * 8;
    const u16* src = (p ? T1o : T1e) + (long long)img * 131072 + k * 512;
    f16x8 a = *(const f16x8*)&src[j0];
    f16x8 b = *(const f16x8*)&src[504 - j0];
    f16x8 br = __builtin_shufflevector(b, b, 7, 6, 5, 4, 3, 2, 1, 0);
    f16x8 s = a + br;
    f16x8 d = a - br;
    long long dst = (long long)img * 131072 + (long long)(2 * k + p) * 256 + j0;
    *(f16x8*)&T1p[dst] = s;
    *(f16x8*)&T1m[dst] = d;
}

// ---------------------------------------------------------------------------
// gemmF2: Ye = T1p @ (B=De), Yo = T1m @ (B=Do).  Y[i][2l'+p], masked tri511.
// id in [0,16): p=id>>3; m0=(sub>>1)*128 (M=512), n0=(sub&1)*128 (N=256).
// Skip fully-masked tiles (m0 + 2*n0 >= 512).
// Epilogue writes ROW-PARITY-SPLIT col-major buffers:
//   YRe[l][i']=Y[2i'][l] (512x256), YRo likewise; plus masked sub-blocks
//   Y2R{e,o} (256x128, tri255) and Y3R{e,o} (128x64, tri127).
// ---------------------------------------------------------------------------
__global__ __launch_bounds__(256) void gemmF2(
    const u16* __restrict__ T1p, const u16* __restrict__ T1m,
    const u16* __restrict__ De, const u16* __restrict__ Do_,
    u16* __restrict__ YRe, u16* __restrict__ YRo,
    u16* __restrict__ Y2Re, u16* __restrict__ Y2Ro,
    u16* __restrict__ Y3Re, u16* __restrict__ Y3Ro)
{
    __shared__ u16 As[2][128 * 32];
    __shared__ u16 Bs[2][128 * 32];
    const int bz = blockIdx.z;
    const int id = blockIdx.x;
    const int p = id >> 3, sub = id & 7;
    const int m0 = (sub >> 1) * 128;
    const int n0 = (sub & 1) * 128;
    if (m0 + 2 * n0 > 511) return;       // fully-masked tile; K-caps downstream never read it

    const u16* __restrict__ Ab = (p ? T1m : T1p) + (long long)bz * 131072;  // lda 256
    const u16* __restrict__ Bb = p ? Do_ : De;                               // ldb 256

    GEMM_DECLS
    GEMM_LOOP(Ab, 256, Bb, 256, 256)

    u16* YReb = YRe + (long long)bz * 131072;
    u16* YRob = YRo + (long long)bz * 131072;
    u16* Y2Reb = Y2Re + (long long)bz * 32768;
    u16* Y2Rob = Y2Ro + (long long)bz * 32768;
    u16* Y3Reb = Y3Re + (long long)bz * 8192;
    u16* Y3Rob = Y3Ro + (long long)bz * 8192;
    #pragma unroll
    for (int i = 0; i < 4; ++i)
        #pragma unroll
        for (int j = 0; j < 4; ++j) {
            int r = m0 + wr + i * 16 + rb;         // Y row base (mult of 4)
            int c = n0 + wc + j * 16 + fr;         // l' index
            int l = 2 * c + p;                     // Y col
            float v0 = ((r + 0) + l <= 511) ? acc[i][j][0] : 0.0f;
            float v1 = ((r + 1) + l <= 511) ? acc[i][j][1] : 0.0f;
            float v2 = ((r + 2) + l <= 511) ? acc[i][j][2] : 0.0f;
            float v3 = ((r + 3) + l <= 511) ? acc[i][j][3] : 0.0f;
            u16 h0 = f2h(v0), h1 = f2h(v1), h2 = f2h(v2), h3 = f2h(v3);
            ushort2 he; he.x = h0; he.y = h2;      // rows r, r+2 (even)
            ushort2 ho; ho.x = h1; ho.y = h3;      // rows r+1, r+3 (odd)
            *(ushort2*)&YReb[(long long)l * 256 + (r >> 1)] = he;
            *(ushort2*)&YRob[(long long)l * 256 + (r >> 1)] = ho;
            if (r < 256 && l < 256) {
                ushort2 h2e, h2o;
                h2e.x = ((r + 0) + l <= 255) ? h0 : (u16)0;
                h2e.y = ((r + 2) + l <= 255) ? h2 : (u16)0;
                h2o.x = ((r + 1) + l <= 255) ? h1 : (u16)0;
                h2o.y = ((r + 3) + l <= 255) ? h3 : (u16)0;
                *(ushort2*)&Y2Reb[(long long)l * 128 + (r >> 1)] = h2e;
                *(ushort2*)&Y2Rob[(long long)l * 128 + (r >> 1)] = h2o;
            }
            if (r < 128 && l < 128) {
                ushort2 h3e, h3o;
                h3e.x = ((r + 0) + l <= 127) ? h0 : (u16)0;
                h3e.y = ((r + 2) + l <= 127) ? h2 : (u16)0;
                h3o.x = ((r + 1) + l <= 127) ? h1 : (u16)0;
                h3o.y = ((r + 3) + l <= 127) ? h3 : (u16)0;
                *(ushort2*)&Y3Reb[(long long)l * 64 + (r >> 1)] = h3e;
                *(ushort2*)&Y3Rob[(long long)l * 64 + (r >> 1)] = h3o;
            }
        }
}

// ---------------------------------------------------------------------------
// invAf: folded first inverse stages. id in [0,28):
//  [0,16):  Ue/Uo[n][l] = sum_{r'} D{e,o}[r'][n] YR{e,o}[l][r']
//           A=D{e,o}T (lda 256), B=YR{e,o} (ldb 256), M=256, N=512,
//           Keff = (512-n0)/2 (mask tri511 K-cap; also guards skipped tiles).
//  [16,24): U2e/U2o: B=Y2R (ldb 128), M=256, N=256, Keff = n0? 64:128.
//  [24,28): U3e/U3o: B=Y3R (ldb 64),  M=256, N=128, K=64.
// Output row-major f16.
// ---------------------------------------------------------------------------
__global__ __launch_bounds__(256) void invAf(
    const u16* __restrict__ DeT, const u16* __restrict__ DoT,
    const u16* __restrict__ YRe, const u16* __restrict__ YRo,
    const u16* __restrict__ Y2Re, const u16* __restrict__ Y2Ro,
    const u16* __restrict__ Y3Re, const u16* __restrict__ Y3Ro,
    u16* __restrict__ Ue, u16* __restrict__ Uo,
    u16* __restrict__ U2e, u16* __restrict__ U2o,
    u16* __restrict__ U3e, u16* __restrict__ U3o)
{
    __shared__ u16 As[2][128 * 32];
    __shared__ u16 Bs[2][128 * 32];
    const int bz = blockIdx.z;
    const int id = blockIdx.x;

    const u16* __restrict__ Ab;
    const u16* __restrict__ Bb;
    u16* __restrict__ Cb;
    int ldb, ldc, Keff, m0, n0;
    if (id < 16) {
        int p = (id >> 3) & 1, sub = id & 7;
        m0 = ((sub >> 2) & 1) * 128; n0 = (sub & 3) * 128;
        Ab = p ? DoT : DeT;
        Bb = (p ? YRo : YRe) + (long long)bz * 131072;  ldb = 256;
        Cb = (p ? Uo : Ue) + (long long)bz * 131072;    ldc = 512;
        Keff = (512 - n0) >> 1;                          // 256,192,128,64
    } else if (id < 24) {
        int t = id - 16;
        int p = t >> 2, sub = t & 3;
        m0 = ((sub >> 1) & 1) * 128; n0 = (sub & 1) * 128;
        Ab = p ? DoT : DeT;
        Bb = (p ? Y2Ro : Y2Re) + (long long)bz * 32768; ldb = 128;
        Cb = (p ? U2o : U2e) + (long long)bz * 65536;   ldc = 256;
        Keff = n0 ? 64 : 128;
    } else {
        int t = id - 24;
        int p = t >> 1;
        m0 = (t & 1) * 128; n0 = 0;
        Ab = p ? DoT : DeT;
        Bb = (p ? Y3Ro : Y3Re) + (long long)bz * 8192;  ldb = 64;
        Cb = (p ? U3o : U3e) + (long long)bz * 32768;   ldc = 128;
        Keff = 64;
    }

    GEMM_DECLS
    GEMM_LOOP(Ab, 256, Bb, ldb, Keff)
    EPI_F16_RM(Cb, ldc)
}

// ---------------------------------------------------------------------------
// foldUs: U[n] = Ue[n]+Uo[n], U[511-n] = Ue[n]-Uo[n] (n<256); same for U2,U3.
// Produces the exact buffers invC consumed in R11 (U 512x512 p512,
// U2 512x256 p256, U3 512x128 p128, all row-major f16).
// ---------------------------------------------------------------------------
__global__ __launch_bounds__(256) void foldUs(
    const u16* __restrict__ Ue, const u16* __restrict__ Uo,
    const u16* __restrict__ U2e, const u16* __restrict__ U2o,
    const u16* __restrict__ U3e, const u16* __restrict__ U3o,
    u16* __restrict__ U, u16* __restrict__ U2, u16* __restrict__ U3)
{
    int t = blockIdx.x * 256 + threadIdx.x;          // 96*28672 total
    int img = t / 28672;
    int rem = t % 28672;
    if (rem < 16384) {
        int m = rem >> 6, j0 = (rem & 63) * 8;
        long long s = (long long)img * 131072 + (long long)m * 512 + j0;
        f16x8 a = *(const f16x8*)&Ue[s];
        f16x8 b = *(const f16x8*)&Uo[s];
        long long dbase = (long long)img * 262144;
        *(f16x8*)&U[dbase + (long long)m * 512 + j0] = a + b;
        *(f16x8*)&U[dbase + (long long)(511 - m) * 512 + j0] = a - b;
    } else if (rem < 24576) {
        int r2 = rem - 16384;
        int m = r2 >> 5, j0 = (r2 & 31) * 8;
        long long s = (long long)img * 65536 + (long long)m * 256 + j0;
        f16x8 a = *(const f16x8*)&U2e[s];
        f16x8 b = *(const f16x8*)&U2o[s];
        long long dbase = (long long)img * 131072;
        *(f16x8*)&U2[dbase + (long long)m * 256 + j0] = a + b;
        *(f16x8*)&U2[dbase + (long long)(511 - m) * 256 + j0] = a - b;
    } else {
        int r3 = rem - 24576;
        int m = r3 >> 4, j0 = (r3 & 15) * 8;
        long long s = (long long)img * 32768 + (long long)m * 128 + j0;
        f16x8 a = *(const f16x8*)&U3e[s];
        f16x8 b = *(const f16x8*)&U3o[s];
        long long dbase = (long long)img * 65536;
        *(f16x8*)&U3[dbase + (long long)m * 128 + j0] = a + b;
        *(f16x8*)&U3[dbase + (long long)(511 - m) * 128 + j0] = a - b;
    }
}

// ---------------------------------------------------------------------------
// invC: UNCHANGED from R11 (proven). Merged S6/S8/S4, fp32 row-major out.
// ---------------------------------------------------------------------------
__global__ __launch_bounds__(256) void invC(
    const u16* __restrict__ U2, const u16* __restrict__ U3,
    const u16* __restrict__ U, const u16* __restrict__ Dcm,
    float* __restrict__ outHL, float* __restrict__ outLH,
    float* __restrict__ outHH)
{
    __shared__ u16 As[2][128 * 32];
    __shared__ u16 Bs[2][128 * 32];
    const int bz = blockIdx.z;
    const int id = blockIdx.x;

    const u16* __restrict__ Ab;
    float* __restrict__ Cb;
    int lda, Keff, m0, n0;
    if (id < 16) {            // S6: HL
        m0 = (id >> 2) * 128; n0 = (id & 3) * 128;
        Ab = U2 + (long long)bz * 131072;  lda = 256; Keff = 256;
        Cb = outHL + (long long)bz * IMG;
    } else if (id < 32) {     // S8: LH
        int t = id - 16;
        m0 = (t >> 2) * 128; n0 = (t & 3) * 128;
        Ab = U3 + (long long)bz * 65536;   lda = 128; Keff = 128;
        Cb = outLH + (long long)bz * IMG;
    } else {                  // S4: HH
        int t = id - 32;
        m0 = (t >> 2) * 128; n0 = (t & 3) * 128;
        Ab = U + (long long)bz * IMG;      lda = 512; Keff = 512;
        Cb = outHH + (long long)bz * IMG;
    }
    const u16* __restrict__ Bb = Dcm;
    const int ldb = 512;
    const int ldc = 512;

    GEMM_DECLS
    GEMM_LOOP(Ab, lda, Bb, ldb, Keff)

    #pragma unroll
    for (int i = 0; i < 4; ++i)
        #pragma unroll
        for (int j = 0; j < 4; ++j) {
            int r = m0 + wr + i * 16 + rb;
            int c = n0 + wc + j * 16 + fr;
            #pragma unroll
            for (int g = 0; g < 4; ++g)
                Cb[(long long)(r + g) * ldc + c] = acc[i][j][g];
        }
}

// ---------------------------------------------------------------------------
// Orchestration (7 dispatches): convF -> gemmF1 -> foldT1 -> gemmF2 ->
// invAf -> foldUs -> invC.
// ws (~196MiB of >=1.5GiB, alias-packed; per-dispatch read/write disjoint):
//  Dcm@0 | De@512K | Do@640K | DeT@768K | DoT@896K |
//  [1MiB,51.4MiB):  Xp|Xm  -> T1p|T1m (after G1) -> U (after G2; 50.3MiB)
//  [51.4,101.7):    T1e|T1o -> Ue|Uo (after foldT1)
//  [101.7,151.9):   YRe|YRo -> U2|U3 (after invAf)
//  [152.0,205.5):   Y2Re|Y2Ro|Y3Re|Y3Ro|U2e|U2o|U3e|U3o
// ---------------------------------------------------------------------------
extern "C" void kernel_launch(void* const* d_in, const int* in_sizes, int n_in,
                              void* d_out, int out_size, void* d_ws, size_t ws_size,
                              hipStream_t stream) {
    const float* x = (const float*)d_in[0];
    float* out = (float*)d_out;
    float* outLL = out + 0 * OUT_PLANE;
    float* outLH = out + 1 * OUT_PLANE;
    float* outHL = out + 2 * OUT_PLANE;
    float* outHH = out + 3 * OUT_PLANE;

    char* ws = (char*)d_ws;
    u16* Dcm = (u16*)(ws);
    u16* De  = (u16*)(ws + 524288);
    u16* Do_ = (u16*)(ws + 655360);
    u16* DeT = (u16*)(ws + 786432);
    u16* DoT = (u16*)(ws + 917504);
    u16* Xp  = (u16*)(ws + 1048576);       // 25165824 B
    u16* Xm  = (u16*)(ws + 26214400);
    u16* T1p = Xp;                          // alias: Xp dead after gemmF1
    u16* T1m = Xm;
    u16* U   = (u16*)(ws + 1048576);       // alias: T1p/T1m dead after gemmF2 (50331648 B)
    u16* T1e = (u16*)(ws + 51380224);
    u16* T1o = (u16*)(ws + 76546048);
    u16* Ue  = T1e;                         // alias: T1e/T1o dead after foldT1
    u16* Uo  = T1o;
    u16* YRe = (u16*)(ws + 101711872);
    u16* YRo = (u16*)(ws + 126877696);
    u16* U2  = YRe;                         // alias: YR dead after invAf
    u16* U3  = YRo;
    u16* Y2Re = (u16*)(ws + 152043520);
    u16* Y2Ro = (u16*)(ws + 158334976);
    u16* Y3Re = (u16*)(ws + 164626432);
    u16* Y3Ro = (u16*)(ws + 166199296);
    u16* U2e  = (u16*)(ws + 167772160);
    u16* U2o  = (u16*)(ws + 180355072);
    u16* U3e  = (u16*)(ws + 192937984);
    u16* U3o  = (u16*)(ws + 199229440);    // end 205520896

    // 1. conv + fold + D-build + LL copy
    convF<<<dim3(16, 8, NIMG), 256, 0, stream>>>(x, Xp, Xm, outLL,
                                                 Dcm, De, Do_, DeT, DoT);
    // 2. T1e/T1o = D{e,o} @ X{p,m}   (K=256)
    gemmF1<<<dim3(16, 1, NIMG), 256, 0, stream>>>(De, Do_, Xp, Xm, T1e, T1o);
    // 3. column fold of T1
    foldT1<<<dim3(6144), 256, 0, stream>>>(T1e, T1o, T1p, T1m);
    // 4. Y (masked, row-parity-split) + Y2/Y3 sub-blocks   (K=256, skip tiles)
    gemmF2<<<dim3(16, 1, NIMG), 256, 0, stream>>>(T1p, T1m, De, Do_,
                                                  YRe, YRo, Y2Re, Y2Ro, Y3Re, Y3Ro);
    // 5. folded first inverse stages (K<=256 with mask K-caps)
    invAf<<<dim3(28, 1, NIMG), 256, 0, stream>>>(DeT, DoT, YRe, YRo,
                                                 Y2Re, Y2Ro, Y3Re, Y3Ro,
                                                 Ue, Uo, U2e, U2o, U3e, U3o);
    // 6. mirror-combine into U/U2/U3
    foldUs<<<dim3(10752), 256, 0, stream>>>(Ue, Uo, U2e, U2o, U3e, U3o, U, U2, U3);
    // 7. second inverse stages -> outHL/outLH/outHH (proven R11 kernel)
    invC<<<dim3(48, 1, NIMG), 256, 0, stream>>>(U2, U3, U, Dcm, outHL, outLH, outHH);
}

// Round 13
// 335.428 us; speedup vs baseline: 1.0705x; 1.0705x over previous
//
#include <hip/hip_runtime.h>
#include <hip/hip_bf16.h>
#include <stdint.h>

#define NIMG 96
#define N 512
#define IMG (N*N)
#define OUT_PLANE ((long long)NIMG * IMG)

typedef __attribute__((ext_vector_type(8))) _Float16 f16x8;
typedef __attribute__((ext_vector_type(4))) float f32x4;
typedef unsigned short u16;

__device__ __forceinline__ u16 f2h(float v) {
    _Float16 h = (_Float16)v;
    return __builtin_bit_cast(u16, h);
}

__device__ __forceinline__ void gload16(const void* g, void* l) {
    __builtin_amdgcn_global_load_lds(
        (const __attribute__((address_space(1))) void*)g,
        (__attribute__((address_space(3))) void*)l, 16, 0, 0);
}

// ---------------------------------------------------------------------------
// conv_x: x fp32 -> Xcm f16 col-major; outLL = x (all-ones mask = identity).
// Blocks with flat id < 1024 also build D (f16, row- and col-major); D is
// only read by later dispatches.
// ---------------------------------------------------------------------------
__global__ __launch_bounds__(256) void conv_x(const float* __restrict__ x,
                                              u16* __restrict__ Xcm,
                                              float* __restrict__ outLL,
                                              u16* __restrict__ Drm,
                                              u16* __restrict__ Dcm) {
    const int bid = blockIdx.x + (blockIdx.y << 4) + (blockIdx.z << 8);
    if (bid < 1024) {
        int idx = (bid << 8) + threadIdx.x;
        int k = idx >> 9, m = idx & 511;
        int r = ((2 * m + 1) * k) & 2047;          // exact angle reduction mod 4N
        float c = cospif((float)r * (1.0f / 1024.0f));
        float s = (k == 0) ? 0.04419417382415922f : 0.0625f;
        u16 h = f2h(c * s);
        Drm[(k << 9) + m] = h;
        Dcm[(m << 9) + k] = h;
    }

    __shared__ float t[32][33];
    const long long base = (long long)blockIdx.z * IMG;
    const int r0 = blockIdx.y * 32, c0 = blockIdx.x * 32;
    const int tr = threadIdx.x >> 3;
    const int tc = (threadIdx.x & 7) * 4;
    float4 v = *(const float4*)&x[base + (long long)(r0 + tr) * N + c0 + tc];
    *(float4*)&outLL[base + (long long)(r0 + tr) * N + c0 + tc] = v;
    t[tr][tc + 0] = v.x; t[tr][tc + 1] = v.y;
    t[tr][tc + 2] = v.z; t[tr][tc + 3] = v.w;
    __syncthreads();
    ushort4 h;
    h.x = f2h(t[tc + 0][tr]); h.y = f2h(t[tc + 1][tr]);
    h.z = f2h(t[tc + 2][tr]); h.w = f2h(t[tc + 3][tr]);
    *(ushort4*)&Xcm[base + (long long)(c0 + tr) * N + r0 + tc] = h;
}

// ===========================================================================
// Proven GEMM engine (R6/R11, 343.7us): 128x128 tile, BK=32, 4 waves,
// dbuf LDS, global_load_lds width-16 staging, mfma_f32_16x16x32_f16,
// 2-barrier __syncthreads loop.
// C = A(row-major) * B(col-major storage: stored[n][k] = op(B)[k][n]).
// ===========================================================================
#define GEMM_DECLS                                                         \
    const int tid = threadIdx.x;                                           \
    const int wave = tid >> 6;                                             \
    const int lane = tid & 63;                                             \
    const int srow = lane >> 2;                                            \
    const int sc8  = (lane & 3) * 8;                                       \
    const int war  = wave * 32;                                            \
    const int fr   = lane & 15;                                            \
    const int kg8  = (lane >> 4) * 8;                                      \
    const int wr   = (wave >> 1) * 64;                                     \
    const int wc   = (wave & 1) * 64;                                      \
    const int rb   = (lane >> 4) * 4;                                      \
    int aoff[4], boff[4];                                                  \
    _Pragma("unroll")                                                      \
    for (int i = 0; i < 4; ++i) {                                          \
        aoff[i] = (wr + i * 16 + fr) * 32 + kg8;                           \
        boff[i] = (wc + i * 16 + fr) * 32 + kg8;                           \
    }                                                                      \
    f32x4 acc[4][4];                                                       \
    _Pragma("unroll")                                                      \
    for (int i = 0; i < 4; ++i)                                            \
        _Pragma("unroll")                                                  \
        for (int j = 0; j < 4; ++j)                                        \
            acc[i][j] = (f32x4){0.0f, 0.0f, 0.0f, 0.0f};

#define GEMM_LOOP(Ab, lda, Bb, ldb, Keff)                                  \
    {                                                                      \
        auto stage = [&](int buf, int k0) {                                \
            _Pragma("unroll")                                              \
            for (int i = 0; i < 2; ++i) {                                  \
                int r = war + i * 16;                                      \
                gload16((Ab) + (long long)(m0 + r + srow) * (lda) + k0 + sc8, &As[buf][r * 32]); \
                gload16((Bb) + (long long)(n0 + r + srow) * (ldb) + k0 + sc8, &Bs[buf][r * 32]); \
            }                                                              \
        };                                                                 \
        auto compute = [&](int buf) {                                      \
            f16x8 af[4], bf[4];                                            \
            _Pragma("unroll")                                              \
            for (int i = 0; i < 4; ++i) af[i] = *(const f16x8*)&As[buf][aoff[i]]; \
            _Pragma("unroll")                                              \
            for (int j = 0; j < 4; ++j) bf[j] = *(const f16x8*)&Bs[buf][boff[j]]; \
            _Pragma("unroll")                                              \
            for (int i = 0; i < 4; ++i)                                    \
                _Pragma("unroll")                                          \
                for (int j = 0; j < 4; ++j)                                \
                    acc[i][j] = __builtin_amdgcn_mfma_f32_16x16x32_f16(af[i], bf[j], acc[i][j], 0, 0, 0); \
        };                                                                 \
        const int nb = (Keff) >> 5;                                        \
        stage(0, 0);                                                       \
        __syncthreads();                                                   \
        int cur = 0;                                                       \
        for (int t = 0; t < nb - 1; ++t) {                                 \
            stage(cur ^ 1, (t + 1) * 32);                                  \
            compute(cur);                                                  \
            __syncthreads();                                               \
            cur ^= 1;                                                      \
        }                                                                  \
        compute(cur);                                                      \
    }

// ---------------------------------------------------------------------------
// gemm16: EPI 1 = f16 row-major (grid y/x tiles);
//         3 = f16 col-major + tri511 mask + fused Y2/Y3 sub-blocks.
//             Launched with a COMPACT grid of the 10 live tiles
//             (flat blockIdx.x LUT; fully-masked tiles never launched).
// ---------------------------------------------------------------------------
template<int EPI>
__global__ __launch_bounds__(256) void gemm16(
    const u16* __restrict__ A, long long sA, int lda,
    const u16* __restrict__ B, long long sB, int ldb,
    void* __restrict__ Cv, long long sC, int ldc,
    int K, int trilim,
    u16* __restrict__ Y2, u16* __restrict__ Y3)
{
    __shared__ u16 As[2][128 * 32];
    __shared__ u16 Bs[2][128 * 32];
    const int bz = blockIdx.z;
    int m0, n0;
    if (EPI == 3) {
        // compact LUT over live tiles of the tri511 mask (ti+tj <= 3)
        int id = blockIdx.x, ti, tj;
        if (id < 4)      { ti = 0; tj = id; }
        else if (id < 7) { ti = 1; tj = id - 4; }
        else if (id < 9) { ti = 2; tj = id - 7; }
        else             { ti = 3; tj = 0; }
        m0 = ti * 128; n0 = tj * 128;
    } else {
        m0 = blockIdx.y * 128;
        n0 = blockIdx.x * 128;
    }

    const u16* __restrict__ Ab = A + (long long)bz * sA;
    const u16* __restrict__ Bb = B + (long long)bz * sB;

    GEMM_DECLS
    GEMM_LOOP(Ab, lda, Bb, ldb, K)

    if (EPI == 1) {
        u16* Cb = (u16*)Cv + (long long)bz * sC;
        #pragma unroll
        for (int i = 0; i < 4; ++i)
            #pragma unroll
            for (int j = 0; j < 4; ++j) {
                int r = m0 + wr + i * 16 + rb;
                int c = n0 + wc + j * 16 + fr;
                #pragma unroll
                for (int g = 0; g < 4; ++g)
                    Cb[(long long)(r + g) * ldc + c] = f2h(acc[i][j][g]);
            }
    } else {
        u16* Cb = (u16*)Cv + (long long)bz * sC;
        u16* Y2b = Y2 + (long long)bz * (256 * 256);
        u16* Y3b = Y3 + (long long)bz * (128 * 128);
        const bool doY2 = (m0 + n0 < 256);        // Y2 zero quadrant never read (kcap)
        #pragma unroll
        for (int i = 0; i < 4; ++i)
            #pragma unroll
            for (int j = 0; j < 4; ++j) {
                int r = m0 + wr + i * 16 + rb;
                int c = n0 + wc + j * 16 + fr;
                float v0 = ((r + 0) + c <= trilim) ? acc[i][j][0] : 0.0f;
                float v1 = ((r + 1) + c <= trilim) ? acc[i][j][1] : 0.0f;
                float v2 = ((r + 2) + c <= trilim) ? acc[i][j][2] : 0.0f;
                float v3 = ((r + 3) + c <= trilim) ? acc[i][j][3] : 0.0f;
                ushort4 h;
                h.x = f2h(v0); h.y = f2h(v1); h.z = f2h(v2); h.w = f2h(v3);
                *(ushort4*)&Cb[(long long)c * ldc + r] = h;   // col-major 8B store
                if (doY2 && r < 256 && c < 256) {
                    ushort4 h2;
                    h2.x = ((r + 0) + c <= 255) ? h.x : (u16)0;
                    h2.y = ((r + 1) + c <= 255) ? h.y : (u16)0;
                    h2.z = ((r + 2) + c <= 255) ? h.z : (u16)0;
                    h2.w = ((r + 3) + c <= 255) ? h.w : (u16)0;
                    *(ushort4*)&Y2b[(long long)c * 256 + r] = h2;
                }
                if (r < 128 && c < 128) {
                    ushort4 h3;
                    h3.x = ((r + 0) + c <= 127) ? h.x : (u16)0;
                    h3.y = ((r + 1) + c <= 127) ? h.y : (u16)0;
                    h3.z = ((r + 2) + c <= 127) ? h.z : (u16)0;
                    h3.w = ((r + 3) + c <= 127) ? h.w : (u16)0;
                    *(ushort4*)&Y3b[(long long)c * 128 + r] = h3;
                }
            }
    }
}

// ---------------------------------------------------------------------------
// invA: merged S3/S5/S7. Flat blockIdx.x in [0,28): [0,16)=S3, [16,24)=S5,
// [24,28)=S7. All write f16 col-major (= U* row-major). A anti-triangular ->
// K early stop (Keff).
// ---------------------------------------------------------------------------
__global__ __launch_bounds__(256) void invA(
    const u16* __restrict__ Ycm, const u16* __restrict__ Y2,
    const u16* __restrict__ Y3, const u16* __restrict__ Dcm,
    u16* __restrict__ U, u16* __restrict__ U2, u16* __restrict__ U3)
{
    __shared__ u16 As[2][128 * 32];
    __shared__ u16 Bs[2][128 * 32];
    const int bz = blockIdx.z;
    const int id = blockIdx.x;

    const u16* __restrict__ Ab;
    u16* __restrict__ Cb;
    int lda, ldc, Keff, m0, n0;
    if (id < 16) {            // S3: U^T = Ym^T @ D   (M=512, K=512-m0)
        m0 = (id >> 2) * 128; n0 = (id & 3) * 128;
        Ab = Ycm + (long long)bz * IMG;     lda = 512;
        Cb = U   + (long long)bz * IMG;     ldc = 512;
        Keff = 512 - m0;
    } else if (id < 24) {     // S5: U2^T = Y2^T @ D[:256,:]  (M=256, K=256-m0)
        int t = id - 16;
        m0 = (t >> 2) * 128; n0 = (t & 3) * 128;
        Ab = Y2 + (long long)bz * 65536;    lda = 256;
        Cb = U2 + (long long)bz * 131072;   ldc = 256;
        Keff = 256 - m0;
    } else {                  // S7: U3^T = Y3^T @ D[:128,:]  (M=128, K=128)
        int t = id - 24;
        m0 = 0;              n0 = (t & 3) * 128;
        Ab = Y3 + (long long)bz * 16384;    lda = 128;
        Cb = U3 + (long long)bz * 65536;    ldc = 128;
        Keff = 128;
    }
    const u16* __restrict__ Bb = Dcm;
    const int ldb = 512;

    GEMM_DECLS
    GEMM_LOOP(Ab, lda, Bb, ldb, Keff)

    #pragma unroll
    for (int i = 0; i < 4; ++i)
        #pragma unroll
        for (int j = 0; j < 4; ++j) {
            int r = m0 + wr + i * 16 + rb;
            int c = n0 + wc + j * 16 + fr;
            ushort4 h;
            h.x = f2h(acc[i][j][0]); h.y = f2h(acc[i][j][1]);
            h.z = f2h(acc[i][j][2]); h.w = f2h(acc[i][j][3]);
            *(ushort4*)&Cb[(long long)c * ldc + r] = h;
        }
}

// ---------------------------------------------------------------------------
// invC: merged S6/S8/S4, fp32 row-major out. Flat blockIdx.x in [0,40):
// [0,16)=S6 (HL = U2 @ D[:256,:], K=256), [16,32)=S8 (LH = U3 @ D[:128,:],
// K=128), [32,40)=S4 (HH = U @ D, K=512) with TWO m-tiles per block
// (amortizes prologue/epilogue over 2x work; pass-2 staging is safe: all
// buf reads complete before pass-1's last pre-epilogue barrier, and the
// loop's own __syncthreads drains pass-2 loads).
// ---------------------------------------------------------------------------
__global__ __launch_bounds__(256) void invC(
    const u16* __restrict__ U2, const u16* __restrict__ U3,
    const u16* __restrict__ U, const u16* __restrict__ Dcm,
    float* __restrict__ outHL, float* __restrict__ outLH,
    float* __restrict__ outHH)
{
    __shared__ u16 As[2][128 * 32];
    __shared__ u16 Bs[2][128 * 32];
    const int bz = blockIdx.z;
    const int id = blockIdx.x;

    const u16* __restrict__ Ab;
    float* __restrict__ Cb;
    int lda, Keff, m0base, n0, npass;
    if (id < 16) {            // S6: HL
        m0base = (id >> 2) * 128; n0 = (id & 3) * 128;
        Ab = U2 + (long long)bz * 131072;  lda = 256; Keff = 256;
        Cb = outHL + (long long)bz * IMG;  npass = 1;
    } else if (id < 32) {     // S8: LH
        int t = id - 16;
        m0base = (t >> 2) * 128; n0 = (t & 3) * 128;
        Ab = U3 + (long long)bz * 65536;   lda = 128; Keff = 128;
        Cb = outLH + (long long)bz * IMG;  npass = 1;
    } else {                  // S4: HH, 2 m-tiles per block
        int t = id - 32;                   // 0..7
        m0base = (t >> 2) * 256; n0 = (t & 3) * 128;
        Ab = U + (long long)bz * IMG;      lda = 512; Keff = 512;
        Cb = outHH + (long long)bz * IMG;  npass = 2;
    }
    const u16* __restrict__ Bb = Dcm;
    const int ldb = 512;
    const int ldc = 512;

    for (int pass = 0; pass < npass; ++pass) {
        const int m0 = m0base + pass * 128;
        GEMM_DECLS
        GEMM_LOOP(Ab, lda, Bb, ldb, Keff)

        #pragma unroll
        for (int i = 0; i < 4; ++i)
            #pragma unroll
            for (int j = 0; j < 4; ++j) {
                int r = m0 + wr + i * 16 + rb;
                int c = n0 + wc + j * 16 + fr;
                #pragma unroll
                for (int g = 0; g < 4; ++g)
                    Cb[(long long)(r + g) * ldc + c] = acc[i][j][g];
            }
        if (pass + 1 < npass) __syncthreads();
    }
}

// ---------------------------------------------------------------------------
// Orchestration (5 dispatches): conv -> S1 -> S2 -> invA -> invC.
// ws layout (poison-fill evidence: ws_size ~1.5GiB; we use 148MiB):
//   Drm @0 (512K) | Dcm @512K (512K) | Xcm/Ycm @1MiB (48MiB) |
//   reg @49MiB (48MiB): T1 (S1->S2) then U (invA->invC) |
//   Y2 @97MiB | Y3 @109MiB | U2 @112MiB | U3 @136MiB
// Race-freedom: invA reads Ycm/Y2/Y3, writes U/U2/U3 (disjoint); invC reads
// U/U2/U3 (read-only), writes the three d_out quarters (disjoint).
// ---------------------------------------------------------------------------
extern "C" void kernel_launch(void* const* d_in, const int* in_sizes, int n_in,
                              void* d_out, int out_size, void* d_ws, size_t ws_size,
                              hipStream_t stream) {
    const float* x = (const float*)d_in[0];
    float* out = (float*)d_out;
    float* outLL = out + 0 * OUT_PLANE;
    float* outLH = out + 1 * OUT_PLANE;
    float* outHL = out + 2 * OUT_PLANE;
    float* outHH = out + 3 * OUT_PLANE;

    char* ws = (char*)d_ws;
    u16* Drm = (u16*)(ws);
    u16* Dcm = (u16*)(ws + 524288);
    u16* Xcm = (u16*)(ws + 1048576);
    u16* Ycm = Xcm;
    char* reg = ws + 51380224;
    u16* T1 = (u16*)reg;
    u16* U  = (u16*)reg;
    u16* Y2 = (u16*)(ws + 101711872);      // 96*256*256 f16 = 12 MiB
    u16* Y3 = (u16*)(ws + 114294784);      // 96*128*128 f16 = 3 MiB
    u16* U2 = (u16*)(ws + 117440512);      // 96*512*256 f16 = 24 MiB
    u16* U3 = (u16*)(ws + 142606336);      // 96*512*128 f16 = 12 MiB

    const long long S = IMG;
    const int BIG = 1 << 30;

    // conv + D-build + LL copy
    conv_x<<<dim3(16, 16, NIMG), 256, 0, stream>>>(x, Xcm, outLL, Drm, Dcm);

    // S1: T1 = D @ X -> f16 row-major
    gemm16<1><<<dim3(4, 4, NIMG), 256, 0, stream>>>(
        Drm, 0, 512, Xcm, S, 512, T1, S, 512, 512, BIG, nullptr, nullptr);
    // S2: Y = T1 @ D^T -> Ycm (tri511) + Y2/Y3; compact grid (10 live tiles)
    gemm16<3><<<dim3(10, 1, NIMG), 256, 0, stream>>>(
        T1, S, 512, Drm, 0, 512, Ycm, S, 512, 512, 511, Y2, Y3);
    // invA: S3 + S5 + S7 -> U, U2, U3 (all ws)
    invA<<<dim3(28, 1, NIMG), 256, 0, stream>>>(Ycm, Y2, Y3, Dcm, U, U2, U3);
    // invC: S6 + S8 + S4(2-pass) -> outHL, outLH, outHH
    invC<<<dim3(40, 1, NIMG), 256, 0, stream>>>(U2, U3, U, Dcm, outHL, outLH, outHH);
}